// Round 1
// baseline (251.001 us; speedup 1.0000x reference)
//
#include <hip/hip_runtime.h>

// Causal attention, fp32, B=8 S=2048 D=64, NO 1/sqrt(d) scaling.
// Flash-style online softmax. Round 1: correctness-first fp32 baseline.
//
// Layout: block = 256 threads handles QT=16 query rows of one batch.
//   thread t: r = t>>4 (row within tile), c = t&15 (column group)
//   scores: thread computes keys j = c + 16*jj (jj=0..3) of each 64-key tile
//   PV:     thread accumulates output dims 4c..4c+3 (P redistributed via LDS)
// Q row lives in registers (64 VGPR). K/V tiles staged in LDS, +4 pad.
// Grid = B * (S/QT) = 1024 blocks, qt reversed so heavy tiles launch first.

#define BATCH 8
#define SEQ 2048
#define DIM 64
#define QT 16
#define KT 64
#define NTHREADS 256
#define LDK (DIM + 4)   // padded stride for sK/sV
#define LDP (KT + 4)    // padded stride for sP

__global__ __launch_bounds__(NTHREADS) void attn_fwd(
    const float* __restrict__ Q, const float* __restrict__ K,
    const float* __restrict__ V, float* __restrict__ O)
{
    const int bid = blockIdx.x;
    const int b   = bid & (BATCH - 1);
    const int qt  = (SEQ / QT - 1) - (bid >> 3);   // heavy (high-qt) tiles first
    const int q0  = qt * QT;

    const int t = threadIdx.x;
    const int r = t >> 4;      // 0..15 query row within tile
    const int c = t & 15;      // 0..15 column group
    const int q_glob = q0 + r;

    __shared__ float sK[KT][LDK];
    __shared__ float sV[KT][LDK];
    __shared__ float sP[QT][LDP];

    const float* Qb = Q + ((size_t)b * SEQ + q0) * DIM;
    const float* Kb = K + (size_t)b * SEQ * DIM;
    const float* Vb = V + (size_t)b * SEQ * DIM;

    // ---- load this thread's full Q row into registers (16 x float4) ----
    float4 qreg[16];
#pragma unroll
    for (int i = 0; i < 16; ++i)
        qreg[i] = *(const float4*)(Qb + r * DIM + i * 4);

    float m = -1e30f;
    float l = 0.0f;
    float4 o = make_float4(0.f, 0.f, 0.f, 0.f);

    const int nkt = (q0 + QT - 1) / KT + 1;   // key tiles needed (causal)

    for (int kt = 0; kt < nkt; ++kt) {
        // ---- stage K/V tile into LDS (coalesced float4) ----
        __syncthreads();   // previous tile fully consumed before overwrite
        {
            const int srow = t >> 4;
            const int scol = (t & 15) * 4;
#pragma unroll
            for (int it = 0; it < 4; ++it) {
                const int rr = srow + it * 16;
                const size_t g = (size_t)(kt * KT + rr) * DIM + scol;
                float4 kv = *(const float4*)(Kb + g);
                float4 vv = *(const float4*)(Vb + g);
                *(float4*)&sK[rr][scol] = kv;
                *(float4*)&sV[rr][scol] = vv;
            }
        }
        __syncthreads();

        // ---- scores for keys j = c + 16*jj over all 64 dims ----
        float s0 = 0.f, s1 = 0.f, s2 = 0.f, s3 = 0.f;
#pragma unroll
        for (int d4 = 0; d4 < 16; ++d4) {
            const int d = d4 * 4;
            float4 qv = qreg[d4];
            float4 k0 = *(const float4*)&sK[c     ][d];
            float4 k1 = *(const float4*)&sK[c + 16][d];
            float4 k2 = *(const float4*)&sK[c + 32][d];
            float4 k3 = *(const float4*)&sK[c + 48][d];
            s0 += qv.x * k0.x + qv.y * k0.y + qv.z * k0.z + qv.w * k0.w;
            s1 += qv.x * k1.x + qv.y * k1.y + qv.z * k1.z + qv.w * k1.w;
            s2 += qv.x * k2.x + qv.y * k2.y + qv.z * k2.z + qv.w * k2.w;
            s3 += qv.x * k3.x + qv.y * k3.y + qv.z * k3.z + qv.w * k3.w;
        }

        // ---- causal mask (finite sentinel avoids inf-inf NaN) ----
        const int kb = kt * KT + c;
        if (kb      > q_glob) s0 = -1e30f;
        if (kb + 16 > q_glob) s1 = -1e30f;
        if (kb + 32 > q_glob) s2 = -1e30f;
        if (kb + 48 > q_glob) s3 = -1e30f;

        // ---- online softmax: row max across the 16 lanes of this row ----
        float mt = fmaxf(fmaxf(s0, s1), fmaxf(s2, s3));
#pragma unroll
        for (int off = 8; off; off >>= 1)
            mt = fmaxf(mt, __shfl_xor(mt, off, 16));
        const float m_new = fmaxf(m, mt);
        const float alpha = __expf(m - m_new);

        const float p0 = __expf(s0 - m_new);
        const float p1 = __expf(s1 - m_new);
        const float p2 = __expf(s2 - m_new);
        const float p3 = __expf(s3 - m_new);
        float ps = p0 + p1 + p2 + p3;
#pragma unroll
        for (int off = 8; off; off >>= 1)
            ps += __shfl_xor(ps, off, 16);

        l = l * alpha + ps;
        m = m_new;
        o.x *= alpha; o.y *= alpha; o.z *= alpha; o.w *= alpha;

        // ---- redistribute P via LDS (key-split -> dim-split) ----
        sP[r][c     ] = p0;
        sP[r][c + 16] = p1;
        sP[r][c + 32] = p2;
        sP[r][c + 48] = p3;
        __syncthreads();   // cross-lane LDS RAW: be safe, full barrier

        // ---- O += P @ V for dims 4c..4c+3 ----
        const int dc = c * 4;
#pragma unroll
        for (int j4 = 0; j4 < KT; j4 += 4) {
            float4 pv = *(const float4*)&sP[r][j4];
            float4 v0 = *(const float4*)&sV[j4 + 0][dc];
            float4 v1 = *(const float4*)&sV[j4 + 1][dc];
            float4 v2 = *(const float4*)&sV[j4 + 2][dc];
            float4 v3 = *(const float4*)&sV[j4 + 3][dc];
            o.x += pv.x * v0.x + pv.y * v1.x + pv.z * v2.x + pv.w * v3.x;
            o.y += pv.x * v0.y + pv.y * v1.y + pv.z * v2.y + pv.w * v3.y;
            o.z += pv.x * v0.z + pv.y * v1.z + pv.z * v2.z + pv.w * v3.z;
            o.w += pv.x * v0.w + pv.y * v1.w + pv.z * v2.w + pv.w * v3.w;
        }
    }

    // ---- epilogue: normalize and store ----
    const float inv_l = 1.0f / l;
    float4 res = make_float4(o.x * inv_l, o.y * inv_l, o.z * inv_l, o.w * inv_l);
    float* Ob = O + ((size_t)b * SEQ + q_glob) * DIM + c * 4;
    *(float4*)Ob = res;
}

extern "C" void kernel_launch(void* const* d_in, const int* in_sizes, int n_in,
                              void* d_out, int out_size, void* d_ws, size_t ws_size,
                              hipStream_t stream) {
    const float* q = (const float*)d_in[0];
    const float* k = (const float*)d_in[1];
    const float* v = (const float*)d_in[2];
    float* out = (float*)d_out;

    dim3 grid(BATCH * (SEQ / QT));   // 1024 blocks
    dim3 block(NTHREADS);
    attn_fwd<<<grid, block, 0, stream>>>(q, k, v, out);
}

// Round 2
// 129.683 us; speedup vs baseline: 1.9355x; 1.9355x over previous
//
#include <hip/hip_runtime.h>

// Causal attention, fp32 in/out, B=8 S=2048 D=64, NO 1/sqrt(d) scaling.
// R2: MFMA flash attention.
//   Pre-pass 1: Q,K -> (hi,lo) bf16 split (3-term product = near-fp32 scores)
//   Pre-pass 2: V -> bf16, transposed per batch: Vt[b][d][s]
//   Main: block = 4 waves, one 16-query tile per block; waves take key-tiles
//   of 64 strided by 4; QK^T and PV on v_mfma_f32_16x16x32_bf16; P goes
//   C-layout -> LDS -> A-layout (m120-verified transform); flash-combine of
//   per-wave (m,l,O) partials through LDS at the end.
// All MFMA operands are 16B contiguous loads in exact fragment layout:
//   A[m][k]: m=lane&15, k=quad*8+j  |  B[k][n]: n=lane&15, k=quad*8+j
//   C/D:     col=lane&15, row=quad*4+reg

#define BATCH 8
#define SEQ 2048
#define DIM 64
#define NEL (BATCH * SEQ * DIM)   // 1,048,576 elements per tensor

typedef __attribute__((ext_vector_type(8))) short short8;
typedef __attribute__((ext_vector_type(4))) float f32x4;

#define MFMA(a, b, c) __builtin_amdgcn_mfma_f32_16x16x32_bf16(a, b, c, 0, 0, 0)

__device__ __forceinline__ unsigned short f2bf(float x) {
    unsigned u = __float_as_uint(x);
    unsigned r = u + 0x7fffu + ((u >> 16) & 1u);   // round-to-nearest-even
    return (unsigned short)(r >> 16);
}
__device__ __forceinline__ float bf2f(unsigned short h) {
    return __uint_as_float(((unsigned)h) << 16);
}
__device__ __forceinline__ short8 ld8(const unsigned short* p) {
    return *(const short8*)p;
}

// ---- pre-pass 1: split-convert Q and K into hi/lo bf16 ----
__global__ __launch_bounds__(256) void convert_qk(
    const float* __restrict__ Q, const float* __restrict__ K,
    unsigned short* __restrict__ Qh, unsigned short* __restrict__ Ql,
    unsigned short* __restrict__ Kh, unsigned short* __restrict__ Kl)
{
    const int tid = blockIdx.x * 256 + threadIdx.x;   // 524288 threads
    const int idx = tid * 4;
    const float* src; unsigned short *dh, *dl; int off;
    if (idx < NEL) { src = Q; dh = Qh; dl = Ql; off = idx; }
    else           { src = K; dh = Kh; dl = Kl; off = idx - NEL; }
    float4 v = *(const float4*)(src + off);
    ushort4 h, l;
    h.x = f2bf(v.x); l.x = f2bf(v.x - bf2f(h.x));
    h.y = f2bf(v.y); l.y = f2bf(v.y - bf2f(h.y));
    h.z = f2bf(v.z); l.z = f2bf(v.z - bf2f(h.z));
    h.w = f2bf(v.w); l.w = f2bf(v.w - bf2f(h.w));
    *(ushort4*)(dh + off) = h;
    *(ushort4*)(dl + off) = l;
}

// ---- pre-pass 2: V[b][s][d] -> Vt[b][d][s] bf16, 64x64 LDS tile ----
__global__ __launch_bounds__(256) void transpose_v(
    const float* __restrict__ V, unsigned short* __restrict__ Vt)
{
    __shared__ unsigned short sT[64][72];
    const int tile = blockIdx.x;            // 8 batches * 32 tiles
    const int b = tile >> 5;
    const int s0 = (tile & 31) * 64;
    const int t = threadIdx.x;

    const int srow = t >> 4;                // 0..15
    const int d4   = (t & 15) * 4;
#pragma unroll
    for (int i = 0; i < 4; ++i) {
        const int row = srow + i * 16;      // key within tile
        float4 v = *(const float4*)(V + ((size_t)(b * SEQ + s0 + row)) * DIM + d4);
        sT[d4 + 0][row] = f2bf(v.x);
        sT[d4 + 1][row] = f2bf(v.y);
        sT[d4 + 2][row] = f2bf(v.z);
        sT[d4 + 3][row] = f2bf(v.w);
    }
    __syncthreads();
    const int d_loc = t & 63;
    const int chunk = t >> 6;               // 0..3, 16 keys each
    unsigned short* dst = Vt + ((size_t)(b * DIM + d_loc)) * SEQ + s0 + chunk * 16;
    const unsigned short* srcp = &sT[d_loc][chunk * 16];
    *(float4*)(dst)     = *(const float4*)(srcp);
    *(float4*)(dst + 8) = *(const float4*)(srcp + 8);
}

// ---- main flash-attention kernel ----
__global__ __launch_bounds__(256) void attn_fwd(
    const unsigned short* __restrict__ Qh, const unsigned short* __restrict__ Ql,
    const unsigned short* __restrict__ Kh, const unsigned short* __restrict__ Kl,
    const unsigned short* __restrict__ Vt, float* __restrict__ O)
{
    __shared__ __align__(16) unsigned short sP[4][16][72];  // per-wave P, bf16
    __shared__ float sO[4][16][68];                         // combine: O partials
    __shared__ float sMl[4][16][2];                         // combine: m,l

    const int bid = blockIdx.x;
    const int b   = bid & (BATCH - 1);
    const int qt  = 127 - (bid >> 3);       // heavy tiles dispatch first
    const int q0  = qt * 16;
    const int nkt = qt / 4 + 1;             // 64-key tiles needed (causal)

    const int t    = threadIdx.x;
    const int w    = t >> 6;                // wave 0..3
    const int lane = t & 63;
    const int quad = lane >> 4;             // 0..3
    const int n16  = lane & 15;             // 0..15

    const int boff = b * SEQ;

    // Q fragments (A-operand): row m = q0+n16, dims chain*32 + quad*8 + j
    const unsigned short* qp = Qh + ((size_t)(boff + q0 + n16)) * DIM + quad * 8;
    const unsigned short* qlp = Ql + ((size_t)(boff + q0 + n16)) * DIM + quad * 8;
    short8 qh0 = ld8(qp),       qh1 = ld8(qp + 32);
    short8 ql0 = ld8(qlp),      ql1 = ld8(qlp + 32);

    float m0 = -1e30f, m1 = -1e30f, m2 = -1e30f, m3 = -1e30f;
    float l0 = 0.f, l1 = 0.f, l2 = 0.f, l3 = 0.f;
    f32x4 oacc[4];
#pragma unroll
    for (int i = 0; i < 4; ++i) oacc[i] = (f32x4){0.f, 0.f, 0.f, 0.f};

    for (int kt = w; kt < nkt; kt += 4) {
        const int kb = kt * 64;

        // ---- scores: 4 subtiles of 16 keys, K=64 (2 chains), 3 split terms ----
        f32x4 sacc[4];
#pragma unroll
        for (int st = 0; st < 4; ++st) {
            const size_t krow = (size_t)(boff + kb + st * 16 + n16) * DIM + quad * 8;
            short8 kh0 = ld8(Kh + krow), kh1 = ld8(Kh + krow + 32);
            short8 kl0 = ld8(Kl + krow), kl1 = ld8(Kl + krow + 32);
            f32x4 acc = (f32x4){0.f, 0.f, 0.f, 0.f};
            acc = MFMA(qh0, kh0, acc);
            acc = MFMA(qh1, kh1, acc);
            acc = MFMA(qh0, kl0, acc);
            acc = MFMA(qh1, kl1, acc);
            acc = MFMA(ql0, kh0, acc);
            acc = MFMA(ql1, kh1, acc);
            sacc[st] = acc;
        }

        // ---- causal mask (only the diagonal tile needs it) ----
        if (kb + 63 > q0) {
#pragma unroll
            for (int st = 0; st < 4; ++st) {
                const int key = kb + st * 16 + n16;
#pragma unroll
                for (int r = 0; r < 4; ++r)
                    if (key > q0 + quad * 4 + r) sacc[st][r] = -1e30f;
            }
        }

        // ---- online softmax (rows = quad*4+r, reduce over 16 lanes of quad) ----
        float mt0 = fmaxf(fmaxf(sacc[0][0], sacc[1][0]), fmaxf(sacc[2][0], sacc[3][0]));
        float mt1 = fmaxf(fmaxf(sacc[0][1], sacc[1][1]), fmaxf(sacc[2][1], sacc[3][1]));
        float mt2 = fmaxf(fmaxf(sacc[0][2], sacc[1][2]), fmaxf(sacc[2][2], sacc[3][2]));
        float mt3 = fmaxf(fmaxf(sacc[0][3], sacc[1][3]), fmaxf(sacc[2][3], sacc[3][3]));
#pragma unroll
        for (int off = 8; off; off >>= 1) {
            mt0 = fmaxf(mt0, __shfl_xor(mt0, off, 16));
            mt1 = fmaxf(mt1, __shfl_xor(mt1, off, 16));
            mt2 = fmaxf(mt2, __shfl_xor(mt2, off, 16));
            mt3 = fmaxf(mt3, __shfl_xor(mt3, off, 16));
        }
        const float mn0 = fmaxf(m0, mt0), mn1 = fmaxf(m1, mt1);
        const float mn2 = fmaxf(m2, mt2), mn3 = fmaxf(m3, mt3);
        const float a0 = __expf(m0 - mn0), a1 = __expf(m1 - mn1);
        const float a2 = __expf(m2 - mn2), a3 = __expf(m3 - mn3);
        m0 = mn0; m1 = mn1; m2 = mn2; m3 = mn3;

        float ps0 = 0.f, ps1 = 0.f, ps2 = 0.f, ps3 = 0.f;
#pragma unroll
        for (int st = 0; st < 4; ++st) {
            const float p0 = __expf(sacc[st][0] - mn0);
            const float p1 = __expf(sacc[st][1] - mn1);
            const float p2 = __expf(sacc[st][2] - mn2);
            const float p3 = __expf(sacc[st][3] - mn3);
            ps0 += p0; ps1 += p1; ps2 += p2; ps3 += p3;
            // P -> LDS in row-major [query][key] bf16 (A-layout readable)
            const int col = st * 16 + n16;
            sP[w][quad * 4 + 0][col] = f2bf(p0);
            sP[w][quad * 4 + 1][col] = f2bf(p1);
            sP[w][quad * 4 + 2][col] = f2bf(p2);
            sP[w][quad * 4 + 3][col] = f2bf(p3);
        }
#pragma unroll
        for (int off = 8; off; off >>= 1) {
            ps0 += __shfl_xor(ps0, off, 16);
            ps1 += __shfl_xor(ps1, off, 16);
            ps2 += __shfl_xor(ps2, off, 16);
            ps3 += __shfl_xor(ps3, off, 16);
        }
        l0 = l0 * a0 + ps0; l1 = l1 * a1 + ps1;
        l2 = l2 * a2 + ps2; l3 = l3 * a3 + ps3;
#pragma unroll
        for (int nt = 0; nt < 4; ++nt) {
            oacc[nt][0] *= a0; oacc[nt][1] *= a1;
            oacc[nt][2] *= a2; oacc[nt][3] *= a3;
        }

        // ---- PV: read P back as A-operand (same wave wrote it; no barrier) ----
        short8 pa0 = ld8(&sP[w][n16][quad * 8]);
        short8 pa1 = ld8(&sP[w][n16][32 + quad * 8]);
#pragma unroll
        for (int nt = 0; nt < 4; ++nt) {
            const size_t vrow = (size_t)(b * DIM + nt * 16 + n16) * SEQ + kb + quad * 8;
            short8 v0 = ld8(Vt + vrow);
            short8 v1 = ld8(Vt + vrow + 32);
            oacc[nt] = MFMA(pa0, v0, oacc[nt]);
            oacc[nt] = MFMA(pa1, v1, oacc[nt]);
        }
    }

    // ---- flash-combine the 4 waves' partials via LDS ----
#pragma unroll
    for (int nt = 0; nt < 4; ++nt)
#pragma unroll
        for (int r = 0; r < 4; ++r)
            sO[w][quad * 4 + r][nt * 16 + n16] = oacc[nt][r];
    if (n16 == 0) {
        sMl[w][quad * 4 + 0][0] = m0; sMl[w][quad * 4 + 0][1] = l0;
        sMl[w][quad * 4 + 1][0] = m1; sMl[w][quad * 4 + 1][1] = l1;
        sMl[w][quad * 4 + 2][0] = m2; sMl[w][quad * 4 + 2][1] = l2;
        sMl[w][quad * 4 + 3][0] = m3; sMl[w][quad * 4 + 3][1] = l3;
    }
    __syncthreads();

    const int row  = t >> 4;          // 0..15
    const int col4 = (t & 15) * 4;    // 0..60
    float M = fmaxf(fmaxf(sMl[0][row][0], sMl[1][row][0]),
                    fmaxf(sMl[2][row][0], sMl[3][row][0]));
    float L = 0.f;
    float ox = 0.f, oy = 0.f, oz = 0.f, ow = 0.f;
#pragma unroll
    for (int wv = 0; wv < 4; ++wv) {
        const float ew = __expf(sMl[wv][row][0] - M);
        L += ew * sMl[wv][row][1];
        const float* op = &sO[wv][row][col4];
        ox += ew * op[0]; oy += ew * op[1]; oz += ew * op[2]; ow += ew * op[3];
    }
    const float inv = 1.0f / L;
    float4 res = make_float4(ox * inv, oy * inv, oz * inv, ow * inv);
    *(float4*)(O + ((size_t)(boff + q0 + row)) * DIM + col4) = res;
}

extern "C" void kernel_launch(void* const* d_in, const int* in_sizes, int n_in,
                              void* d_out, int out_size, void* d_ws, size_t ws_size,
                              hipStream_t stream) {
    const float* q = (const float*)d_in[0];
    const float* k = (const float*)d_in[1];
    const float* v = (const float*)d_in[2];
    float* out = (float*)d_out;

    unsigned short* Qh = (unsigned short*)d_ws;
    unsigned short* Ql = Qh + NEL;
    unsigned short* Kh = Ql + NEL;
    unsigned short* Kl = Kh + NEL;
    unsigned short* Vt = Kl + NEL;   // 10 MB total in d_ws

    convert_qk<<<dim3(2 * NEL / 4 / 256), dim3(256), 0, stream>>>(q, k, Qh, Ql, Kh, Kl);
    transpose_v<<<dim3(BATCH * (SEQ / 64)), dim3(256), 0, stream>>>(v, Vt);
    attn_fwd<<<dim3(BATCH * (SEQ / 16)), dim3(256), 0, stream>>>(Qh, Ql, Kh, Kl, Vt, out);
}

// Round 4
// 122.901 us; speedup vs baseline: 2.0423x; 1.0552x over previous
//
#include <hip/hip_runtime.h>

// Causal attention, fp32 in/out, B=8 S=2048 D=64, NO 1/sqrt(d) scaling.
// R4 = R3 with the causal-mask guard fixed: mask whenever kb+127 > q0
// (R3's `rem < 127` skipped masking for chunks overlapping the *upper*
// query rows but not the lowest one -> absmax 3.6).
// Fragment layouts (verified in R2):
//   A[m][k]: m=lane&15, k=quad*8+j | B[k][n]: n=lane&15, k=quad*8+j
//   C/D:     col=lane&15, row=quad*4+reg

#define BATCH 8
#define SEQ 2048
#define DIM 64
#define NEL (BATCH * SEQ * DIM)   // 1,048,576 elements per tensor

typedef __attribute__((ext_vector_type(8))) short short8;
typedef __attribute__((ext_vector_type(4))) float f32x4;

#define MFMA(a, b, c) __builtin_amdgcn_mfma_f32_16x16x32_bf16(a, b, c, 0, 0, 0)

__device__ __forceinline__ unsigned short f2bf(float x) {
    unsigned u = __float_as_uint(x);
    unsigned r = u + 0x7fffu + ((u >> 16) & 1u);   // RNE
    return (unsigned short)(r >> 16);
}
__device__ __forceinline__ float bf2f(unsigned short h) {
    return __uint_as_float(((unsigned)h) << 16);
}
__device__ __forceinline__ short8 ld8(const unsigned short* p) {
    return *(const short8*)p;
}

// ---- fused pre-pass: Q/K hi-lo split convert + V bf16 transpose ----
// blocks [0, 2048): convert Q,K   | blocks [2048, 2304): transpose V
__global__ __launch_bounds__(256) void prep(
    const float* __restrict__ Q, const float* __restrict__ K,
    const float* __restrict__ V,
    unsigned short* __restrict__ Qh, unsigned short* __restrict__ Ql,
    unsigned short* __restrict__ Kh, unsigned short* __restrict__ Kl,
    unsigned short* __restrict__ Vt)
{
    __shared__ unsigned short sT[64][72];
    const int blk = blockIdx.x;
    const int t = threadIdx.x;

    if (blk < 2048) {
        const int idx = (blk * 256 + t) * 4;
        const float* src; unsigned short *dh, *dl; int off;
        if (idx < NEL) { src = Q; dh = Qh; dl = Ql; off = idx; }
        else           { src = K; dh = Kh; dl = Kl; off = idx - NEL; }
        float4 v = *(const float4*)(src + off);
        ushort4 h, l;
        h.x = f2bf(v.x); l.x = f2bf(v.x - bf2f(h.x));
        h.y = f2bf(v.y); l.y = f2bf(v.y - bf2f(h.y));
        h.z = f2bf(v.z); l.z = f2bf(v.z - bf2f(h.z));
        h.w = f2bf(v.w); l.w = f2bf(v.w - bf2f(h.w));
        *(ushort4*)(dh + off) = h;
        *(ushort4*)(dl + off) = l;
        return;
    }

    const int tile = blk - 2048;            // 8 batches * 32 tiles
    const int b = tile >> 5;
    const int s0 = (tile & 31) * 64;
    const int srow = t >> 4;
    const int d4   = (t & 15) * 4;
#pragma unroll
    for (int i = 0; i < 4; ++i) {
        const int row = srow + i * 16;
        float4 v = *(const float4*)(V + ((size_t)(b * SEQ + s0 + row)) * DIM + d4);
        sT[d4 + 0][row] = f2bf(v.x);
        sT[d4 + 1][row] = f2bf(v.y);
        sT[d4 + 2][row] = f2bf(v.z);
        sT[d4 + 3][row] = f2bf(v.w);
    }
    __syncthreads();
    const int d_loc = t & 63;
    const int chunk = t >> 6;
    unsigned short* dst = Vt + ((size_t)(b * DIM + d_loc)) * SEQ + s0 + chunk * 16;
    const unsigned short* srcp = &sT[d_loc][chunk * 16];
    *(float4*)(dst)     = *(const float4*)(srcp);
    *(float4*)(dst + 8) = *(const float4*)(srcp + 8);
}

// ---- main flash-attention kernel: 128-key chunks per wave-iteration ----
__global__ __launch_bounds__(256) void attn_main(
    const unsigned short* __restrict__ Qh, const unsigned short* __restrict__ Ql,
    const unsigned short* __restrict__ Kh, const unsigned short* __restrict__ Kl,
    const unsigned short* __restrict__ Vt, float* __restrict__ O)
{
    __shared__ __align__(16) unsigned short sP[4][16][136];  // 128 keys + pad
    __shared__ float sO[4][16][68];
    __shared__ float sMl[4][16][2];

    const int bid = blockIdx.x;
    const int b   = bid & (BATCH - 1);
    const int qt  = 127 - (bid >> 3);       // heavy tiles dispatch first
    const int q0  = qt * 16;
    const int q_max = q0 + 15;

    const int t    = threadIdx.x;
    const int w    = t >> 6;
    const int lane = t & 63;
    const int quad = lane >> 4;
    const int n16  = lane & 15;
    const int boff = b * SEQ;

    const unsigned short* qp  = Qh + ((size_t)(boff + q0 + n16)) * DIM + quad * 8;
    const unsigned short* qlp = Ql + ((size_t)(boff + q0 + n16)) * DIM + quad * 8;
    short8 qh0 = ld8(qp),  qh1 = ld8(qp + 32);
    short8 ql0 = ld8(qlp), ql1 = ld8(qlp + 32);

    float m0 = -1e30f, m1 = -1e30f, m2 = -1e30f, m3 = -1e30f;
    float l0 = 0.f, l1 = 0.f, l2 = 0.f, l3 = 0.f;
    f32x4 oacc[4];
#pragma unroll
    for (int i = 0; i < 4; ++i) oacc[i] = (f32x4){0.f, 0.f, 0.f, 0.f};

    for (int kb = w * 128; kb <= q_max; kb += 512) {
        const int rem  = q_max - kb;               // >= 0
        const int nsub = min(8, (rem >> 4) + 1);   // valid 16-key subtiles
        const int nchain = (nsub + 1) >> 1;        // valid 32-key PV chains
        f32x4 sacc[8];

        // ---- QK^T: 8 subtiles in pairs (8 loads in flight per pair) ----
#pragma unroll
        for (int gp = 0; gp < 4; ++gp) {
            const int stA = 2 * gp, stB = stA + 1;
            if (stA < nsub) {
                const size_t krA = (size_t)(boff + kb + stA * 16 + n16) * DIM + quad * 8;
                short8 khA0 = ld8(Kh + krA), khA1 = ld8(Kh + krA + 32);
                short8 klA0 = ld8(Kl + krA), klA1 = ld8(Kl + krA + 32);
                const bool okB = (stB < nsub);
                const size_t krB = (size_t)(boff + kb + stB * 16 + n16) * DIM + quad * 8;
                short8 khB0, khB1, klB0, klB1;
                if (okB) {
                    khB0 = ld8(Kh + krB); khB1 = ld8(Kh + krB + 32);
                    klB0 = ld8(Kl + krB); klB1 = ld8(Kl + krB + 32);
                }
                f32x4 accA = (f32x4){0.f, 0.f, 0.f, 0.f};
                accA = MFMA(qh0, khA0, accA);
                accA = MFMA(qh1, khA1, accA);
                accA = MFMA(qh0, klA0, accA);
                accA = MFMA(qh1, klA1, accA);
                accA = MFMA(ql0, khA0, accA);
                accA = MFMA(ql1, khA1, accA);
                sacc[stA] = accA;
                if (okB) {
                    f32x4 accB = (f32x4){0.f, 0.f, 0.f, 0.f};
                    accB = MFMA(qh0, khB0, accB);
                    accB = MFMA(qh1, khB1, accB);
                    accB = MFMA(qh0, klB0, accB);
                    accB = MFMA(qh1, klB1, accB);
                    accB = MFMA(ql0, khB0, accB);
                    accB = MFMA(ql1, khB1, accB);
                    sacc[stB] = accB;
                } else {
                    sacc[stB] = (f32x4){-1e30f, -1e30f, -1e30f, -1e30f};
                }
            } else {
                sacc[stA] = (f32x4){-1e30f, -1e30f, -1e30f, -1e30f};
                sacc[stB] = (f32x4){-1e30f, -1e30f, -1e30f, -1e30f};
            }
        }

        // ---- causal mask: any chunk overlapping ANY query row ----
        if (kb + 127 > q0) {     // R4 FIX (was: rem < 127)
#pragma unroll
            for (int st = 0; st < 8; ++st) {
                if (st < nsub) {
                    const int key = kb + st * 16 + n16;
#pragma unroll
                    for (int r = 0; r < 4; ++r)
                        if (key > q0 + quad * 4 + r) sacc[st][r] = -1e30f;
                }
            }
        }

        // ---- online softmax over 128 keys (one chain per chunk) ----
        float mt0 = sacc[0][0], mt1 = sacc[0][1], mt2 = sacc[0][2], mt3 = sacc[0][3];
#pragma unroll
        for (int st = 1; st < 8; ++st) {
            mt0 = fmaxf(mt0, sacc[st][0]);
            mt1 = fmaxf(mt1, sacc[st][1]);
            mt2 = fmaxf(mt2, sacc[st][2]);
            mt3 = fmaxf(mt3, sacc[st][3]);
        }
#pragma unroll
        for (int off = 8; off; off >>= 1) {
            mt0 = fmaxf(mt0, __shfl_xor(mt0, off, 16));
            mt1 = fmaxf(mt1, __shfl_xor(mt1, off, 16));
            mt2 = fmaxf(mt2, __shfl_xor(mt2, off, 16));
            mt3 = fmaxf(mt3, __shfl_xor(mt3, off, 16));
        }
        const float mn0 = fmaxf(m0, mt0), mn1 = fmaxf(m1, mt1);
        const float mn2 = fmaxf(m2, mt2), mn3 = fmaxf(m3, mt3);
        const float a0 = __expf(m0 - mn0), a1 = __expf(m1 - mn1);
        const float a2 = __expf(m2 - mn2), a3 = __expf(m3 - mn3);
        m0 = mn0; m1 = mn1; m2 = mn2; m3 = mn3;

        float ps0 = 0.f, ps1 = 0.f, ps2 = 0.f, ps3 = 0.f;
        const int stmax = 2 * nchain;   // subtiles that PV will read
#pragma unroll
        for (int st = 0; st < 8; ++st) {
            if (st < stmax) {
                float p0 = 0.f, p1 = 0.f, p2 = 0.f, p3 = 0.f;
                if (st < nsub) {
                    p0 = __expf(sacc[st][0] - mn0);
                    p1 = __expf(sacc[st][1] - mn1);
                    p2 = __expf(sacc[st][2] - mn2);
                    p3 = __expf(sacc[st][3] - mn3);
                    ps0 += p0; ps1 += p1; ps2 += p2; ps3 += p3;
                }
                const int col = st * 16 + n16;
                sP[w][quad * 4 + 0][col] = f2bf(p0);
                sP[w][quad * 4 + 1][col] = f2bf(p1);
                sP[w][quad * 4 + 2][col] = f2bf(p2);
                sP[w][quad * 4 + 3][col] = f2bf(p3);
            }
        }
#pragma unroll
        for (int off = 8; off; off >>= 1) {
            ps0 += __shfl_xor(ps0, off, 16);
            ps1 += __shfl_xor(ps1, off, 16);
            ps2 += __shfl_xor(ps2, off, 16);
            ps3 += __shfl_xor(ps3, off, 16);
        }
        l0 = l0 * a0 + ps0; l1 = l1 * a1 + ps1;
        l2 = l2 * a2 + ps2; l3 = l3 * a3 + ps3;
#pragma unroll
        for (int nt = 0; nt < 4; ++nt) {
            oacc[nt][0] *= a0; oacc[nt][1] *= a1;
            oacc[nt][2] *= a2; oacc[nt][3] *= a3;
        }

        // ---- PV over valid 32-key chains (same-wave LDS, no barrier) ----
#pragma unroll
        for (int ch = 0; ch < 4; ++ch) {
            if (ch < nchain) {
                short8 pa = ld8(&sP[w][n16][ch * 32 + quad * 8]);
#pragma unroll
                for (int nt = 0; nt < 4; ++nt) {
                    const size_t vrow =
                        (size_t)(b * DIM + nt * 16 + n16) * SEQ + kb + ch * 32 + quad * 8;
                    short8 vv = ld8(Vt + vrow);
                    oacc[nt] = MFMA(pa, vv, oacc[nt]);
                }
            }
        }
    }

    // ---- flash-combine the 4 waves' partials ----
#pragma unroll
    for (int nt = 0; nt < 4; ++nt)
#pragma unroll
        for (int r = 0; r < 4; ++r)
            sO[w][quad * 4 + r][nt * 16 + n16] = oacc[nt][r];
    if (n16 == 0) {
        sMl[w][quad * 4 + 0][0] = m0; sMl[w][quad * 4 + 0][1] = l0;
        sMl[w][quad * 4 + 1][0] = m1; sMl[w][quad * 4 + 1][1] = l1;
        sMl[w][quad * 4 + 2][0] = m2; sMl[w][quad * 4 + 2][1] = l2;
        sMl[w][quad * 4 + 3][0] = m3; sMl[w][quad * 4 + 3][1] = l3;
    }
    __syncthreads();

    const int row  = t >> 4;
    const int col4 = (t & 15) * 4;
    float M = fmaxf(fmaxf(sMl[0][row][0], sMl[1][row][0]),
                    fmaxf(sMl[2][row][0], sMl[3][row][0]));
    float L = 0.f;
    float ox = 0.f, oy = 0.f, oz = 0.f, ow = 0.f;
#pragma unroll
    for (int wv = 0; wv < 4; ++wv) {
        const float ew = __expf(sMl[wv][row][0] - M);
        L += ew * sMl[wv][row][1];
        const float* op = &sO[wv][row][col4];
        ox += ew * op[0]; oy += ew * op[1]; oz += ew * op[2]; ow += ew * op[3];
    }
    const float inv = 1.0f / L;
    float4 res = make_float4(ox * inv, oy * inv, oz * inv, ow * inv);
    *(float4*)(O + ((size_t)(boff + q0 + row)) * DIM + col4) = res;
}

extern "C" void kernel_launch(void* const* d_in, const int* in_sizes, int n_in,
                              void* d_out, int out_size, void* d_ws, size_t ws_size,
                              hipStream_t stream) {
    const float* q = (const float*)d_in[0];
    const float* k = (const float*)d_in[1];
    const float* v = (const float*)d_in[2];
    float* out = (float*)d_out;

    unsigned short* Qh = (unsigned short*)d_ws;
    unsigned short* Ql = Qh + NEL;
    unsigned short* Kh = Ql + NEL;
    unsigned short* Kl = Kh + NEL;
    unsigned short* Vt = Kl + NEL;   // 10 MB total in d_ws

    prep<<<dim3(2048 + 256), dim3(256), 0, stream>>>(q, k, v, Qh, Ql, Kh, Kl, Vt);
    attn_main<<<dim3(BATCH * (SEQ / 16)), dim3(256), 0, stream>>>(Qh, Ql, Kh, Kl, Vt, out);
}

// Round 5
// 120.574 us; speedup vs baseline: 2.0817x; 1.0193x over previous
//
#include <hip/hip_runtime.h>

// Causal attention, fp32 in/out, B=8 S=2048 D=64, NO 1/sqrt(d) scaling.
// R5: (1) triangle pairing — block processes q-tiles {i, 127-i} sequentially,
// so EVERY block does exactly 17 128-key chunks (R4's 16:1 block imbalance
// with zero oversubscription left ~75% of CUs idle most of the kernel).
// (2) DPP butterfly reductions (quad_perm/row_half_mirror/row_mirror) replace
// __shfl_xor trees (~2-4 cyc vs ~120 cyc ds_swizzle) in the softmax chain.
// (3) sP/sO union scratch: LDS 35 KB -> 18 KB.
// Fragment layouts (verified R2):
//   A[m][k]: m=lane&15, k=quad*8+j | B[k][n]: n=lane&15, k=quad*8+j
//   C/D:     col=lane&15, row=quad*4+reg

#define BATCH 8
#define SEQ 2048
#define DIM 64
#define NEL (BATCH * SEQ * DIM)

typedef __attribute__((ext_vector_type(8))) short short8;
typedef __attribute__((ext_vector_type(4))) float f32x4;

#define MFMA(a, b, c) __builtin_amdgcn_mfma_f32_16x16x32_bf16(a, b, c, 0, 0, 0)

__device__ __forceinline__ unsigned short f2bf(float x) {
    unsigned u = __float_as_uint(x);
    unsigned r = u + 0x7fffu + ((u >> 16) & 1u);   // RNE
    return (unsigned short)(r >> 16);
}
__device__ __forceinline__ float bf2f(unsigned short h) {
    return __uint_as_float(((unsigned)h) << 16);
}
__device__ __forceinline__ short8 ld8(const unsigned short* p) {
    return *(const short8*)p;
}

// DPP butterfly reduce over each 16-lane row (max / sum); result in all lanes.
// ctrls: xor1=quad_perm(1,0,3,2)=0xB1, xor2=quad_perm(2,3,0,1)=0x4E,
// cross4=row_half_mirror=0x141, cross8=row_mirror=0x140.
__device__ __forceinline__ float dpp_max16(float x) {
    float o;
    o = __int_as_float(__builtin_amdgcn_update_dpp(0, __float_as_int(x), 0xB1, 0xF, 0xF, true));
    x = fmaxf(x, o);
    o = __int_as_float(__builtin_amdgcn_update_dpp(0, __float_as_int(x), 0x4E, 0xF, 0xF, true));
    x = fmaxf(x, o);
    o = __int_as_float(__builtin_amdgcn_update_dpp(0, __float_as_int(x), 0x141, 0xF, 0xF, true));
    x = fmaxf(x, o);
    o = __int_as_float(__builtin_amdgcn_update_dpp(0, __float_as_int(x), 0x140, 0xF, 0xF, true));
    return fmaxf(x, o);
}
__device__ __forceinline__ float dpp_sum16(float x) {
    float o;
    o = __int_as_float(__builtin_amdgcn_update_dpp(0, __float_as_int(x), 0xB1, 0xF, 0xF, true));
    x += o;
    o = __int_as_float(__builtin_amdgcn_update_dpp(0, __float_as_int(x), 0x4E, 0xF, 0xF, true));
    x += o;
    o = __int_as_float(__builtin_amdgcn_update_dpp(0, __float_as_int(x), 0x141, 0xF, 0xF, true));
    x += o;
    o = __int_as_float(__builtin_amdgcn_update_dpp(0, __float_as_int(x), 0x140, 0xF, 0xF, true));
    return x + o;
}

// ---- fused pre-pass: Q/K hi-lo split convert + V bf16 transpose ----
__global__ __launch_bounds__(256) void prep(
    const float* __restrict__ Q, const float* __restrict__ K,
    const float* __restrict__ V,
    unsigned short* __restrict__ Qh, unsigned short* __restrict__ Ql,
    unsigned short* __restrict__ Kh, unsigned short* __restrict__ Kl,
    unsigned short* __restrict__ Vt)
{
    __shared__ unsigned short sT[64][72];
    const int blk = blockIdx.x;
    const int t = threadIdx.x;

    if (blk < 2048) {
        const int idx = (blk * 256 + t) * 4;
        const float* src; unsigned short *dh, *dl; int off;
        if (idx < NEL) { src = Q; dh = Qh; dl = Ql; off = idx; }
        else           { src = K; dh = Kh; dl = Kl; off = idx - NEL; }
        float4 v = *(const float4*)(src + off);
        ushort4 h, l;
        h.x = f2bf(v.x); l.x = f2bf(v.x - bf2f(h.x));
        h.y = f2bf(v.y); l.y = f2bf(v.y - bf2f(h.y));
        h.z = f2bf(v.z); l.z = f2bf(v.z - bf2f(h.z));
        h.w = f2bf(v.w); l.w = f2bf(v.w - bf2f(h.w));
        *(ushort4*)(dh + off) = h;
        *(ushort4*)(dl + off) = l;
        return;
    }

    const int tile = blk - 2048;
    const int b = tile >> 5;
    const int s0 = (tile & 31) * 64;
    const int srow = t >> 4;
    const int d4   = (t & 15) * 4;
#pragma unroll
    for (int i = 0; i < 4; ++i) {
        const int row = srow + i * 16;
        float4 v = *(const float4*)(V + ((size_t)(b * SEQ + s0 + row)) * DIM + d4);
        sT[d4 + 0][row] = f2bf(v.x);
        sT[d4 + 1][row] = f2bf(v.y);
        sT[d4 + 2][row] = f2bf(v.z);
        sT[d4 + 3][row] = f2bf(v.w);
    }
    __syncthreads();
    const int d_loc = t & 63;
    const int chunk = t >> 6;
    unsigned short* dst = Vt + ((size_t)(b * DIM + d_loc)) * SEQ + s0 + chunk * 16;
    const unsigned short* srcp = &sT[d_loc][chunk * 16];
    *(float4*)(dst)     = *(const float4*)(srcp);
    *(float4*)(dst + 8) = *(const float4*)(srcp + 8);
}

// ---- main kernel: 512 blocks, each does q-tiles {pair, 127-pair} ----
__global__ __launch_bounds__(256) void attn_main(
    const unsigned short* __restrict__ Qh, const unsigned short* __restrict__ Ql,
    const unsigned short* __restrict__ Kh, const unsigned short* __restrict__ Kl,
    const unsigned short* __restrict__ Vt, float* __restrict__ O)
{
    // union scratch: per-wave sP (ushort[16][136]=4352B) == sO (float[16][68]=4352B)
    __shared__ __align__(16) char scratch[4][4352];
    __shared__ float sMl[4][16][2];

    const int bid  = blockIdx.x;
    const int b    = bid & (BATCH - 1);
    const int pair = bid >> 3;              // 0..63

    const int t    = threadIdx.x;
    const int w    = t >> 6;
    const int lane = t & 63;
    const int quad = lane >> 4;
    const int n16  = lane & 15;
    const int boff = b * SEQ;

    unsigned short* sPw = (unsigned short*)scratch[w];   // [16][136]
    float*          sOw = (float*)scratch[w];            // [16][68]

    for (int half = 0; half < 2; ++half) {
        const int qt = half ? (127 - pair) : pair;
        const int q0 = qt * 16;
        const int q_max = q0 + 15;

        const unsigned short* qp  = Qh + ((size_t)(boff + q0 + n16)) * DIM + quad * 8;
        const unsigned short* qlp = Ql + ((size_t)(boff + q0 + n16)) * DIM + quad * 8;
        short8 qh0 = ld8(qp),  qh1 = ld8(qp + 32);
        short8 ql0 = ld8(qlp), ql1 = ld8(qlp + 32);

        float m0 = -1e30f, m1 = -1e30f, m2 = -1e30f, m3 = -1e30f;
        float l0 = 0.f, l1 = 0.f, l2 = 0.f, l3 = 0.f;
        f32x4 oacc[4];
#pragma unroll
        for (int i = 0; i < 4; ++i) oacc[i] = (f32x4){0.f, 0.f, 0.f, 0.f};

        for (int kb = w * 128; kb <= q_max; kb += 512) {
            const int rem  = q_max - kb;
            const int nsub = min(8, (rem >> 4) + 1);
            const int nchain = (nsub + 1) >> 1;
            f32x4 sacc[8];

            // ---- QK^T: 8 subtiles in pairs ----
#pragma unroll
            for (int gp = 0; gp < 4; ++gp) {
                const int stA = 2 * gp, stB = stA + 1;
                if (stA < nsub) {
                    const size_t krA = (size_t)(boff + kb + stA * 16 + n16) * DIM + quad * 8;
                    short8 khA0 = ld8(Kh + krA), khA1 = ld8(Kh + krA + 32);
                    short8 klA0 = ld8(Kl + krA), klA1 = ld8(Kl + krA + 32);
                    const bool okB = (stB < nsub);
                    const size_t krB = (size_t)(boff + kb + stB * 16 + n16) * DIM + quad * 8;
                    short8 khB0, khB1, klB0, klB1;
                    if (okB) {
                        khB0 = ld8(Kh + krB); khB1 = ld8(Kh + krB + 32);
                        klB0 = ld8(Kl + krB); klB1 = ld8(Kl + krB + 32);
                    }
                    f32x4 accA = (f32x4){0.f, 0.f, 0.f, 0.f};
                    accA = MFMA(qh0, khA0, accA);
                    accA = MFMA(qh1, khA1, accA);
                    accA = MFMA(qh0, klA0, accA);
                    accA = MFMA(qh1, klA1, accA);
                    accA = MFMA(ql0, khA0, accA);
                    accA = MFMA(ql1, khA1, accA);
                    sacc[stA] = accA;
                    if (okB) {
                        f32x4 accB = (f32x4){0.f, 0.f, 0.f, 0.f};
                        accB = MFMA(qh0, khB0, accB);
                        accB = MFMA(qh1, khB1, accB);
                        accB = MFMA(qh0, klB0, accB);
                        accB = MFMA(qh1, klB1, accB);
                        accB = MFMA(ql0, khB0, accB);
                        accB = MFMA(ql1, khB1, accB);
                        sacc[stB] = accB;
                    } else {
                        sacc[stB] = (f32x4){-1e30f, -1e30f, -1e30f, -1e30f};
                    }
                } else {
                    sacc[stA] = (f32x4){-1e30f, -1e30f, -1e30f, -1e30f};
                    sacc[stB] = (f32x4){-1e30f, -1e30f, -1e30f, -1e30f};
                }
            }

            // ---- causal mask: any chunk overlapping any query row ----
            if (kb + 127 > q0) {
#pragma unroll
                for (int st = 0; st < 8; ++st) {
                    if (st < nsub) {
                        const int key = kb + st * 16 + n16;
#pragma unroll
                        for (int r = 0; r < 4; ++r)
                            if (key > q0 + quad * 4 + r) sacc[st][r] = -1e30f;
                    }
                }
            }

            // ---- online softmax over 128 keys, DPP reductions ----
            float mt0 = sacc[0][0], mt1 = sacc[0][1], mt2 = sacc[0][2], mt3 = sacc[0][3];
#pragma unroll
            for (int st = 1; st < 8; ++st) {
                mt0 = fmaxf(mt0, sacc[st][0]);
                mt1 = fmaxf(mt1, sacc[st][1]);
                mt2 = fmaxf(mt2, sacc[st][2]);
                mt3 = fmaxf(mt3, sacc[st][3]);
            }
            mt0 = dpp_max16(mt0); mt1 = dpp_max16(mt1);
            mt2 = dpp_max16(mt2); mt3 = dpp_max16(mt3);
            const float mn0 = fmaxf(m0, mt0), mn1 = fmaxf(m1, mt1);
            const float mn2 = fmaxf(m2, mt2), mn3 = fmaxf(m3, mt3);
            const float a0 = __expf(m0 - mn0), a1 = __expf(m1 - mn1);
            const float a2 = __expf(m2 - mn2), a3 = __expf(m3 - mn3);
            m0 = mn0; m1 = mn1; m2 = mn2; m3 = mn3;

            float ps0 = 0.f, ps1 = 0.f, ps2 = 0.f, ps3 = 0.f;
            const int stmax = 2 * nchain;
#pragma unroll
            for (int st = 0; st < 8; ++st) {
                if (st < stmax) {
                    float p0 = 0.f, p1 = 0.f, p2 = 0.f, p3 = 0.f;
                    if (st < nsub) {
                        p0 = __expf(sacc[st][0] - mn0);
                        p1 = __expf(sacc[st][1] - mn1);
                        p2 = __expf(sacc[st][2] - mn2);
                        p3 = __expf(sacc[st][3] - mn3);
                        ps0 += p0; ps1 += p1; ps2 += p2; ps3 += p3;
                    }
                    const int col = st * 16 + n16;
                    sPw[(quad * 4 + 0) * 136 + col] = f2bf(p0);
                    sPw[(quad * 4 + 1) * 136 + col] = f2bf(p1);
                    sPw[(quad * 4 + 2) * 136 + col] = f2bf(p2);
                    sPw[(quad * 4 + 3) * 136 + col] = f2bf(p3);
                }
            }
            ps0 = dpp_sum16(ps0); ps1 = dpp_sum16(ps1);
            ps2 = dpp_sum16(ps2); ps3 = dpp_sum16(ps3);
            l0 = l0 * a0 + ps0; l1 = l1 * a1 + ps1;
            l2 = l2 * a2 + ps2; l3 = l3 * a3 + ps3;
#pragma unroll
            for (int nt = 0; nt < 4; ++nt) {
                oacc[nt][0] *= a0; oacc[nt][1] *= a1;
                oacc[nt][2] *= a2; oacc[nt][3] *= a3;
            }

            // ---- PV over valid 32-key chains (same-wave LDS) ----
#pragma unroll
            for (int ch = 0; ch < 4; ++ch) {
                if (ch < nchain) {
                    short8 pa = ld8(&sPw[n16 * 136 + ch * 32 + quad * 8]);
#pragma unroll
                    for (int nt = 0; nt < 4; ++nt) {
                        const size_t vrow =
                            (size_t)(b * DIM + nt * 16 + n16) * SEQ + kb + ch * 32 + quad * 8;
                        short8 vv = ld8(Vt + vrow);
                        oacc[nt] = MFMA(pa, vv, oacc[nt]);
                    }
                }
            }
        }

        // ---- flash-combine the 4 waves' partials (sO overlays sP) ----
#pragma unroll
        for (int nt = 0; nt < 4; ++nt)
#pragma unroll
            for (int r = 0; r < 4; ++r)
                sOw[(quad * 4 + r) * 68 + nt * 16 + n16] = oacc[nt][r];
        if (n16 == 0) {
            sMl[w][quad * 4 + 0][0] = m0; sMl[w][quad * 4 + 0][1] = l0;
            sMl[w][quad * 4 + 1][0] = m1; sMl[w][quad * 4 + 1][1] = l1;
            sMl[w][quad * 4 + 2][0] = m2; sMl[w][quad * 4 + 2][1] = l2;
            sMl[w][quad * 4 + 3][0] = m3; sMl[w][quad * 4 + 3][1] = l3;
        }
        __syncthreads();

        const int row  = t >> 4;
        const int col4 = (t & 15) * 4;
        float M = fmaxf(fmaxf(sMl[0][row][0], sMl[1][row][0]),
                        fmaxf(sMl[2][row][0], sMl[3][row][0]));
        float L = 0.f;
        float ox = 0.f, oy = 0.f, oz = 0.f, ow = 0.f;
#pragma unroll
        for (int wv = 0; wv < 4; ++wv) {
            const float ew = __expf(sMl[wv][row][0] - M);
            L += ew * sMl[wv][row][1];
            const float* op = (const float*)scratch[wv] + row * 68 + col4;
            ox += ew * op[0]; oy += ew * op[1]; oz += ew * op[2]; ow += ew * op[3];
        }
        const float inv = 1.0f / L;
        float4 res = make_float4(ox * inv, oy * inv, oz * inv, ow * inv);
        *(float4*)(O + ((size_t)(boff + q0 + row)) * DIM + col4) = res;

        __syncthreads();   // scratch reused as sP by the next half
    }
}

extern "C" void kernel_launch(void* const* d_in, const int* in_sizes, int n_in,
                              void* d_out, int out_size, void* d_ws, size_t ws_size,
                              hipStream_t stream) {
    const float* q = (const float*)d_in[0];
    const float* k = (const float*)d_in[1];
    const float* v = (const float*)d_in[2];
    float* out = (float*)d_out;

    unsigned short* Qh = (unsigned short*)d_ws;
    unsigned short* Ql = Qh + NEL;
    unsigned short* Kh = Ql + NEL;
    unsigned short* Kl = Kh + NEL;
    unsigned short* Vt = Kl + NEL;   // 10 MB total in d_ws

    prep<<<dim3(2048 + 256), dim3(256), 0, stream>>>(q, k, v, Qh, Ql, Kh, Kl, Vt);
    attn_main<<<dim3(512), dim3(256), 0, stream>>>(Qh, Ql, Kh, Kl, Vt, out);
}